// Round 1
// baseline (496.016 us; speedup 1.0000x reference)
//
#include <hip/hip_runtime.h>
#include <hip/hip_bf16.h>

#define D 128

typedef __bf16 bf16x8 __attribute__((ext_vector_type(8)));
typedef float f32x4 __attribute__((ext_vector_type(4)));

__device__ __forceinline__ unsigned short f2bf(float f) {
    unsigned u = __float_as_uint(f);
    u += 0x7FFFu + ((u >> 16) & 1u);
    return (unsigned short)(u >> 16);
}
__device__ __forceinline__ float bf2f(unsigned short h) {
    return __uint_as_float(((unsigned)h) << 16);
}

// Build W = [W_nbrs | W_self]^T as bf16, XOR-swizzled so GEMM can stage it
// linearly into LDS and read B fragments conflict-free.
// Element (k, c) -> WTs[c*128 + (((k>>3) ^ (c&15)) << 3) + (k&7)]
__global__ void k_build_wt(const float* __restrict__ Wn, const float* __restrict__ Ws,
                           unsigned short* __restrict__ WTs) {
    int g = blockIdx.x * blockDim.x + threadIdx.x;   // 0..32767
    int k = g >> 8;          // 0..127
    int c = g & 255;         // 0..255 (coalesced reads along c)
    float v = (c < 128) ? Wn[k * 128 + c] : Ws[k * 128 + (c - 128)];
    int chunk = k >> 3;
    WTs[c * 128 + (((chunk ^ (c & 15)) << 3) | (k & 7))] = f2bf(v);
}

__global__ void k_hist(const int* __restrict__ dst, int E, int* __restrict__ cnt) {
    int e = blockIdx.x * blockDim.x + threadIdx.x;
    if (e < E) atomicAdd(&cnt[dst[e]], 1);
}

__global__ void k_scanA(const int* __restrict__ cnt, int N,
                        int* __restrict__ ofs, int* __restrict__ bsum) {
    __shared__ int lds[1024];
    int t = threadIdx.x, i = blockIdx.x * 1024 + t;
    int v = (i < N) ? cnt[i] : 0;
    lds[t] = v; __syncthreads();
    for (int d = 1; d < 1024; d <<= 1) {
        int x = (t >= d) ? lds[t - d] : 0; __syncthreads();
        lds[t] += x; __syncthreads();
    }
    if (i < N) ofs[i] = lds[t] - v;
    if (t == 1023) bsum[blockIdx.x] = lds[t];
}

__global__ void k_scanB(int* __restrict__ bsum, int NB) {   // NB <= 128
    __shared__ int lds[128];
    int t = threadIdx.x;
    int v = (t < NB) ? bsum[t] : 0;
    lds[t] = v; __syncthreads();
    for (int d = 1; d < 128; d <<= 1) {
        int x = (t >= d) ? lds[t - d] : 0; __syncthreads();
        lds[t] += x; __syncthreads();
    }
    if (t < NB) bsum[t] = lds[t] - v;
}

__global__ void k_scanC(int N, const int* __restrict__ bsum,
                        int* __restrict__ ofs, int* __restrict__ cur) {
    int t = threadIdx.x, i = blockIdx.x * 1024 + t;
    if (i < N) { int o = ofs[i] + bsum[blockIdx.x]; ofs[i] = o; cur[i] = o; }
}

__global__ void k_fill(const int* __restrict__ src, const int* __restrict__ dst,
                       const float* __restrict__ w, int E, int* __restrict__ cur,
                       uint2* __restrict__ sorted) {
    int e = blockIdx.x * blockDim.x + threadIdx.x;
    if (e < E) {
        int d = dst[e];
        int pos = atomicAdd(&cur[d], 1);
        sorted[pos] = make_uint2((unsigned)src[e], __float_as_uint(w[e]));
    }
}

// 64 rows per WG (4 waves x 16 rows), full K=128, 256 output cols (both W's).
// y (cols 0..127) -> bf16 scratch; out (cols 128..255 => x@W_self + bias) -> d_out.
__global__ __launch_bounds__(256) void k_gemm(
    const float* __restrict__ x, const unsigned short* __restrict__ WTs,
    const float* __restrict__ bias, int N,
    unsigned short* __restrict__ y, float* __restrict__ out) {
    extern __shared__ unsigned short sm[];   // 256*128 bf16 = 64 KB
    int tid = threadIdx.x;
    {   // linear stage of pre-swizzled WT: conflict-free b128 writes
        const uint4* gs = (const uint4*)WTs;
        uint4* ss = (uint4*)sm;
        #pragma unroll
        for (int r = 0; r < 16; ++r) ss[r * 256 + tid] = gs[r * 256 + tid];
    }
    int w = tid >> 6, l = tid & 63;
    int row0 = blockIdx.x * 64 + w * 16;
    int c15 = l & 15;
    int kgrp = l >> 4;                       // 0..3
    int arow = row0 + c15;                   // A: row = lane%16
    bool avalid = (arow < N);
    const float* xr = x + (size_t)arow * D;
    bf16x8 afrag[4];
    #pragma unroll
    for (int ks = 0; ks < 4; ++ks) {
        int k0 = ks * 32 + kgrp * 8;         // A: k = 8*(lane/16) + j
        float4 a0, a1;
        if (avalid) { a0 = *(const float4*)(xr + k0); a1 = *(const float4*)(xr + k0 + 4); }
        else { a0 = make_float4(0.f, 0.f, 0.f, 0.f); a1 = a0; }
        bf16x8 f;
        f[0] = (__bf16)a0.x; f[1] = (__bf16)a0.y; f[2] = (__bf16)a0.z; f[3] = (__bf16)a0.w;
        f[4] = (__bf16)a1.x; f[5] = (__bf16)a1.y; f[6] = (__bf16)a1.z; f[7] = (__bf16)a1.w;
        afrag[ks] = f;
    }
    __syncthreads();
    int orow = row0 + kgrp * 4;              // C/D: row = 4*(lane/16) + j
    #pragma unroll
    for (int nt = 0; nt < 16; ++nt) {
        int c = nt * 16 + c15;               // B/C/D col = lane%16
        f32x4 acc = {0.f, 0.f, 0.f, 0.f};
        #pragma unroll
        for (int ks = 0; ks < 4; ++ks) {
            int chunk = ks * 4 + kgrp;       // B: k = 8*(lane/16)+j within 32-K step
            const bf16x8* bp = (const bf16x8*)(sm + c * 128 + ((chunk ^ c15) << 3));
            acc = __builtin_amdgcn_mfma_f32_16x16x32_bf16(afrag[ks], *bp, acc, 0, 0, 0);
        }
        if (nt < 8) {
            #pragma unroll
            for (int j = 0; j < 4; ++j) {
                int r = orow + j;
                if (r < N) y[(size_t)r * D + c] = f2bf(acc[j]);
            }
        } else {
            int co = c - 128;
            float b = bias[co];
            #pragma unroll
            for (int j = 0; j < 4; ++j) {
                int r = orow + j;
                if (r < N) out[(size_t)r * D + co] = acc[j] + b;
            }
        }
    }
}

// One wave per destination node; 2 features per lane; register accumulation;
// single RMW of out at the end (out already holds x@W_self + bias).
__global__ __launch_bounds__(256) void k_agg(
    const unsigned short* __restrict__ y, const uint2* __restrict__ sorted,
    const int* __restrict__ ofs, const int* __restrict__ cnt, int N,
    float* __restrict__ out) {
    int w = threadIdx.x >> 6, l = threadIdx.x & 63;
    int node = blockIdx.x * 4 + w;
    if (node >= N) return;
    int s = ofs[node], n = cnt[node];
    const unsigned* y32 = (const unsigned*)y;
    float ax = 0.f, ay = 0.f;
    for (int j = 0; j < n; ++j) {
        uint2 p = sorted[s + j];             // wave-uniform 8B load
        float wt = __uint_as_float(p.y);
        unsigned v = y32[(size_t)p.x * 64 + l];  // coalesced 256B row gather
        ax += wt * bf2f((unsigned short)(v & 0xFFFFu));
        ay += wt * bf2f((unsigned short)(v >> 16));
    }
    float2* op = (float2*)(out + (size_t)node * D + 2 * l);
    float2 o = *op;
    o.x += ax; o.y += ay;
    *op = o;
}

extern "C" void kernel_launch(void* const* d_in, const int* in_sizes, int n_in,
                              void* d_out, int out_size, void* d_ws, size_t ws_size,
                              hipStream_t stream) {
    const float* x    = (const float*)d_in[0];
    const int*   esrc = (const int*)d_in[1];
    const int*   edst = (const int*)d_in[2];
    const float* ew   = (const float*)d_in[3];
    const float* Wn   = (const float*)d_in[4];
    const float* Wsf  = (const float*)d_in[5];
    const float* bias = (const float*)d_in[6];
    float* out = (float*)d_out;
    int N = in_sizes[0] / D;
    int E = in_sizes[1];

    char* ws = (char*)d_ws;
    size_t off = 0;
    unsigned short* WTs = (unsigned short*)(ws + off); off += 256 * 128 * sizeof(unsigned short);
    unsigned short* yb  = (unsigned short*)(ws + off); off += (size_t)N * D * sizeof(unsigned short);
    off = (off + 255) & ~(size_t)255;
    int* cnt  = (int*)(ws + off); off += (size_t)N * 4; off = (off + 255) & ~(size_t)255;
    int* ofs  = (int*)(ws + off); off += (size_t)N * 4; off = (off + 255) & ~(size_t)255;
    int* cur  = (int*)(ws + off); off += (size_t)N * 4; off = (off + 255) & ~(size_t)255;
    int* bsum = (int*)(ws + off); off += 1024;
    uint2* sorted = (uint2*)(ws + off); off += (size_t)E * 8;

    hipMemsetAsync(cnt, 0, (size_t)N * 4, stream);

    k_build_wt<<<128, 256, 0, stream>>>(Wn, Wsf, WTs);
    k_gemm<<<(N + 63) / 64, 256, 65536, stream>>>(x, WTs, bias, N, yb, out);

    k_hist<<<(E + 255) / 256, 256, 0, stream>>>(edst, E, cnt);
    int NB = (N + 1023) / 1024;
    k_scanA<<<NB, 1024, 0, stream>>>(cnt, N, ofs, bsum);
    k_scanB<<<1, 128, 0, stream>>>(bsum, NB);
    k_scanC<<<NB, 1024, 0, stream>>>(N, bsum, ofs, cur);
    k_fill<<<(E + 255) / 256, 256, 0, stream>>>(esrc, edst, ew, E, cur, sorted);

    k_agg<<<(N + 3) / 4, 256, 0, stream>>>(yb, sorted, ofs, cnt, N, out);
}

// Round 2
// 393.316 us; speedup vs baseline: 1.2611x; 1.2611x over previous
//
#include <hip/hip_runtime.h>
#include <hip/hip_bf16.h>

#define D 128

typedef __bf16 bf16x8 __attribute__((ext_vector_type(8)));
typedef float f32x4 __attribute__((ext_vector_type(4)));

__device__ __forceinline__ unsigned short f2bf(float f) {
    unsigned u = __float_as_uint(f);
    u += 0x7FFFu + ((u >> 16) & 1u);
    return (unsigned short)(u >> 16);
}
__device__ __forceinline__ float bf2f(unsigned u16) {
    return __uint_as_float(u16 << 16);
}

// Build W = [W_nbrs | W_self]^T as bf16, XOR-swizzled so GEMM can stage it
// linearly into LDS and read B fragments conflict-free.
// Element (k, c) -> WTs[c*128 + (((k>>3) ^ (c&15)) << 3) + (k&7)]
__global__ void k_build_wt(const float* __restrict__ Wn, const float* __restrict__ Ws,
                           unsigned short* __restrict__ WTs) {
    int g = blockIdx.x * blockDim.x + threadIdx.x;   // 0..32767
    int k = g >> 8;          // 0..127
    int c = g & 255;         // 0..255 (coalesced reads along c)
    float v = (c < 128) ? Wn[k * 128 + c] : Ws[k * 128 + (c - 128)];
    int chunk = k >> 3;
    WTs[c * 128 + (((chunk ^ (c & 15)) << 3) | (k & 7))] = f2bf(v);
}

__global__ void k_hist(const int* __restrict__ dst, int E, int* __restrict__ cnt) {
    int e = blockIdx.x * blockDim.x + threadIdx.x;
    if (e < E) atomicAdd(&cnt[dst[e]], 1);
}

__global__ void k_scanA(const int* __restrict__ cnt, int N,
                        int* __restrict__ ofs, int* __restrict__ bsum) {
    __shared__ int lds[1024];
    int t = threadIdx.x, i = blockIdx.x * 1024 + t;
    int v = (i < N) ? cnt[i] : 0;
    lds[t] = v; __syncthreads();
    for (int d = 1; d < 1024; d <<= 1) {
        int x = (t >= d) ? lds[t - d] : 0; __syncthreads();
        lds[t] += x; __syncthreads();
    }
    if (i < N) ofs[i] = lds[t] - v;
    if (t == 1023) bsum[blockIdx.x] = lds[t];
}

__global__ void k_scanB(int* __restrict__ bsum, int NB) {   // NB <= 128
    __shared__ int lds[128];
    int t = threadIdx.x;
    int v = (t < NB) ? bsum[t] : 0;
    lds[t] = v; __syncthreads();
    for (int d = 1; d < 128; d <<= 1) {
        int x = (t >= d) ? lds[t - d] : 0; __syncthreads();
        lds[t] += x; __syncthreads();
    }
    if (t < NB) bsum[t] = lds[t] - v;
}

__global__ void k_scanC(int N, const int* __restrict__ bsum,
                        int* __restrict__ ofs, int* __restrict__ cur) {
    int t = threadIdx.x, i = blockIdx.x * 1024 + t;
    if (i < N) { int o = ofs[i] + bsum[blockIdx.x]; ofs[i] = o; cur[i] = o; }
}

__global__ void k_fill(const int* __restrict__ src, const int* __restrict__ dst,
                       const float* __restrict__ w, int E, int* __restrict__ cur,
                       uint2* __restrict__ sorted) {
    int e = blockIdx.x * blockDim.x + threadIdx.x;
    if (e < E) {
        int d = dst[e];
        int pos = atomicAdd(&cur[d], 1);
        sorted[pos] = make_uint2((unsigned)src[e], __float_as_uint(w[e]));
    }
}

// 64 rows per WG (4 waves x 16 rows), full K=128, 256 output cols, in two
// 128-col phases so LDS is 32 KB -> 4 blocks/CU (16 waves) instead of 2.
// Phase 0 (cols 0..127 = x@W_nbrs) -> bf16 y; phase 1 (x@W_self + bias) -> out.
__global__ __launch_bounds__(256) void k_gemm(
    const float* __restrict__ x, const unsigned short* __restrict__ WTs,
    const float* __restrict__ bias, int N,
    unsigned short* __restrict__ y, float* __restrict__ out) {
    __shared__ unsigned short sm[128 * 128];   // 32 KB
    int tid = threadIdx.x;
    int w = tid >> 6, l = tid & 63;
    int row0 = blockIdx.x * 64 + w * 16;
    int c15 = l & 15;
    int kgrp = l >> 4;                       // 0..3
    const uint4* gs = (const uint4*)WTs;
    uint4* ss = (uint4*)sm;
    {   // stage phase-0 half of WT: linear, conflict-free b128 writes
        #pragma unroll
        for (int r = 0; r < 8; ++r) ss[r * 256 + tid] = gs[r * 256 + tid];
    }
    int arow = row0 + c15;                   // A: row = lane%16
    bool avalid = (arow < N);
    const float* xr = x + (size_t)arow * D;
    bf16x8 afrag[4];
    #pragma unroll
    for (int ks = 0; ks < 4; ++ks) {
        int k0 = ks * 32 + kgrp * 8;         // A: k = 8*(lane/16) + j
        float4 a0, a1;
        if (avalid) { a0 = *(const float4*)(xr + k0); a1 = *(const float4*)(xr + k0 + 4); }
        else { a0 = make_float4(0.f, 0.f, 0.f, 0.f); a1 = a0; }
        bf16x8 f;
        f[0] = (__bf16)a0.x; f[1] = (__bf16)a0.y; f[2] = (__bf16)a0.z; f[3] = (__bf16)a0.w;
        f[4] = (__bf16)a1.x; f[5] = (__bf16)a1.y; f[6] = (__bf16)a1.z; f[7] = (__bf16)a1.w;
        afrag[ks] = f;
    }
    __syncthreads();
    int orow = row0 + kgrp * 4;              // C/D: row = 4*(lane/16) + j
    #pragma unroll
    for (int nt = 0; nt < 8; ++nt) {         // phase 0: y
        int c = nt * 16 + c15;
        f32x4 acc = {0.f, 0.f, 0.f, 0.f};
        #pragma unroll
        for (int ks = 0; ks < 4; ++ks) {
            int chunk = ks * 4 + kgrp;
            const bf16x8* bp = (const bf16x8*)(sm + c * 128 + ((chunk ^ c15) << 3));
            acc = __builtin_amdgcn_mfma_f32_16x16x32_bf16(afrag[ks], *bp, acc, 0, 0, 0);
        }
        #pragma unroll
        for (int j = 0; j < 4; ++j) {
            int r = orow + j;
            if (r < N) y[(size_t)r * D + c] = f2bf(acc[j]);
        }
    }
    __syncthreads();
    {   // stage phase-1 half
        #pragma unroll
        for (int r = 0; r < 8; ++r) ss[r * 256 + tid] = gs[2048 + r * 256 + tid];
    }
    __syncthreads();
    #pragma unroll
    for (int nt = 0; nt < 8; ++nt) {         // phase 1: out = x@W_self + bias
        int c = nt * 16 + c15;
        f32x4 acc = {0.f, 0.f, 0.f, 0.f};
        #pragma unroll
        for (int ks = 0; ks < 4; ++ks) {
            int chunk = ks * 4 + kgrp;
            const bf16x8* bp = (const bf16x8*)(sm + c * 128 + ((chunk ^ c15) << 3));
            acc = __builtin_amdgcn_mfma_f32_16x16x32_bf16(afrag[ks], *bp, acc, 0, 0, 0);
        }
        float b = bias[c];
        #pragma unroll
        for (int j = 0; j < 4; ++j) {
            int r = orow + j;
            if (r < N) out[(size_t)r * D + c] = acc[j] + b;
        }
    }
}

// One wave per destination node, split into 4 x 16-lane groups.
// Group g handles edges j = g, g+4, ... ; each lane loads 16 B (8 bf16 feats),
// so 4 row-gathers are in flight per iteration (8 with unroll-2).
// End: 2-round shfl_xor butterfly, lanes 0..15 wide-RMW out (512 B/wave).
__global__ __launch_bounds__(256) void k_agg(
    const unsigned short* __restrict__ y, const uint2* __restrict__ sorted,
    const int* __restrict__ ofs, const int* __restrict__ cnt, int N,
    float* __restrict__ out) {
    int w = threadIdx.x >> 6, l = threadIdx.x & 63;
    int node = blockIdx.x * 4 + w;
    if (node >= N) return;
    int s = ofs[node], n = cnt[node];
    int g = l >> 4, li = l & 15;
    const uint2* sp = sorted + s;
    float a0 = 0.f, a1 = 0.f, a2 = 0.f, a3 = 0.f;
    float a4 = 0.f, a5 = 0.f, a6 = 0.f, a7 = 0.f;
    int j = g;
    for (; j + 4 < n; j += 8) {
        uint2 pa = sp[j];
        uint2 pb = sp[j + 4];
        uint4 va = *(const uint4*)(y + (size_t)pa.x * D + li * 8);
        uint4 vb = *(const uint4*)(y + (size_t)pb.x * D + li * 8);
        float wa = __uint_as_float(pa.y), wb = __uint_as_float(pb.y);
        a0 += wa * bf2f(va.x & 0xFFFFu); a1 += wa * bf2f(va.x >> 16);
        a2 += wa * bf2f(va.y & 0xFFFFu); a3 += wa * bf2f(va.y >> 16);
        a4 += wa * bf2f(va.z & 0xFFFFu); a5 += wa * bf2f(va.z >> 16);
        a6 += wa * bf2f(va.w & 0xFFFFu); a7 += wa * bf2f(va.w >> 16);
        a0 += wb * bf2f(vb.x & 0xFFFFu); a1 += wb * bf2f(vb.x >> 16);
        a2 += wb * bf2f(vb.y & 0xFFFFu); a3 += wb * bf2f(vb.y >> 16);
        a4 += wb * bf2f(vb.z & 0xFFFFu); a5 += wb * bf2f(vb.z >> 16);
        a6 += wb * bf2f(vb.w & 0xFFFFu); a7 += wb * bf2f(vb.w >> 16);
    }
    if (j < n) {
        uint2 p = sp[j];
        uint4 v = *(const uint4*)(y + (size_t)p.x * D + li * 8);
        float wt = __uint_as_float(p.y);
        a0 += wt * bf2f(v.x & 0xFFFFu); a1 += wt * bf2f(v.x >> 16);
        a2 += wt * bf2f(v.y & 0xFFFFu); a3 += wt * bf2f(v.y >> 16);
        a4 += wt * bf2f(v.z & 0xFFFFu); a5 += wt * bf2f(v.z >> 16);
        a6 += wt * bf2f(v.w & 0xFFFFu); a7 += wt * bf2f(v.w >> 16);
    }
    // butterfly across the 4 groups (xor 16, then xor 32): all lanes -> full sums
    a0 += __shfl_xor(a0, 16, 64); a1 += __shfl_xor(a1, 16, 64);
    a2 += __shfl_xor(a2, 16, 64); a3 += __shfl_xor(a3, 16, 64);
    a4 += __shfl_xor(a4, 16, 64); a5 += __shfl_xor(a5, 16, 64);
    a6 += __shfl_xor(a6, 16, 64); a7 += __shfl_xor(a7, 16, 64);
    a0 += __shfl_xor(a0, 32, 64); a1 += __shfl_xor(a1, 32, 64);
    a2 += __shfl_xor(a2, 32, 64); a3 += __shfl_xor(a3, 32, 64);
    a4 += __shfl_xor(a4, 32, 64); a5 += __shfl_xor(a5, 32, 64);
    a6 += __shfl_xor(a6, 32, 64); a7 += __shfl_xor(a7, 32, 64);
    if (l < 16) {   // lanes 0..15 each own features [li*8, li*8+8)
        float4* op = (float4*)(out + (size_t)node * D + li * 8);
        float4 o0 = op[0], o1 = op[1];
        o0.x += a0; o0.y += a1; o0.z += a2; o0.w += a3;
        o1.x += a4; o1.y += a5; o1.z += a6; o1.w += a7;
        op[0] = o0; op[1] = o1;
    }
}

extern "C" void kernel_launch(void* const* d_in, const int* in_sizes, int n_in,
                              void* d_out, int out_size, void* d_ws, size_t ws_size,
                              hipStream_t stream) {
    const float* x    = (const float*)d_in[0];
    const int*   esrc = (const int*)d_in[1];
    const int*   edst = (const int*)d_in[2];
    const float* ew   = (const float*)d_in[3];
    const float* Wn   = (const float*)d_in[4];
    const float* Wsf  = (const float*)d_in[5];
    const float* bias = (const float*)d_in[6];
    float* out = (float*)d_out;
    int N = in_sizes[0] / D;
    int E = in_sizes[1];

    char* ws = (char*)d_ws;
    size_t off = 0;
    unsigned short* WTs = (unsigned short*)(ws + off); off += 256 * 128 * sizeof(unsigned short);
    unsigned short* yb  = (unsigned short*)(ws + off); off += (size_t)N * D * sizeof(unsigned short);
    off = (off + 255) & ~(size_t)255;
    int* cnt  = (int*)(ws + off); off += (size_t)N * 4; off = (off + 255) & ~(size_t)255;
    int* ofs  = (int*)(ws + off); off += (size_t)N * 4; off = (off + 255) & ~(size_t)255;
    int* cur  = (int*)(ws + off); off += (size_t)N * 4; off = (off + 255) & ~(size_t)255;
    int* bsum = (int*)(ws + off); off += 1024;
    uint2* sorted = (uint2*)(ws + off); off += (size_t)E * 8;

    hipMemsetAsync(cnt, 0, (size_t)N * 4, stream);

    k_build_wt<<<128, 256, 0, stream>>>(Wn, Wsf, WTs);
    k_gemm<<<(N + 63) / 64, 256, 0, stream>>>(x, WTs, bias, N, yb, out);

    k_hist<<<(E + 255) / 256, 256, 0, stream>>>(edst, E, cnt);
    int NB = (N + 1023) / 1024;
    k_scanA<<<NB, 1024, 0, stream>>>(cnt, N, ofs, bsum);
    k_scanB<<<1, 128, 0, stream>>>(bsum, NB);
    k_scanC<<<NB, 1024, 0, stream>>>(N, bsum, ofs, cur);
    k_fill<<<(E + 255) / 256, 256, 0, stream>>>(esrc, edst, ew, E, cur, sorted);

    k_agg<<<(N + 3) / 4, 256, 0, stream>>>(yb, sorted, ofs, cnt, N, out);
}

// Round 3
// 304.039 us; speedup vs baseline: 1.6314x; 1.2936x over previous
//
#include <hip/hip_runtime.h>
#include <hip/hip_bf16.h>

#define D 128

typedef __bf16 bf16x8 __attribute__((ext_vector_type(8)));
typedef float f32x4 __attribute__((ext_vector_type(4)));

__device__ __forceinline__ unsigned short f2bf(float f) {
    unsigned u = __float_as_uint(f);
    u += 0x7FFFu + ((u >> 16) & 1u);
    return (unsigned short)(u >> 16);
}
__device__ __forceinline__ float bf2f(unsigned u16) {
    return __uint_as_float(u16 << 16);
}

// Build W = [W_nbrs | W_self]^T as bf16, XOR-swizzled so GEMM can stage it
// linearly into LDS and read B fragments conflict-free.
// Element (k, c) -> WTs[c*128 + (((k>>3) ^ (c&15)) << 3) + (k&7)]
__global__ void k_build_wt(const float* __restrict__ Wn, const float* __restrict__ Ws,
                           unsigned short* __restrict__ WTs) {
    int g = blockIdx.x * blockDim.x + threadIdx.x;   // 0..32767
    int k = g >> 8;          // 0..127
    int c = g & 255;         // 0..255 (coalesced reads along c)
    float v = (c < 128) ? Wn[k * 128 + c] : Ws[k * 128 + (c - 128)];
    int chunk = k >> 3;
    WTs[c * 128 + (((chunk ^ (c & 15)) << 3) | (k & 7))] = f2bf(v);
}

// Fused: blocks with blockIdx%5==0 run the GEMM tile (64 rows), the other 4/5
// run the rank pass (rank[e] = atomicAdd(&cnt[dst],1)). GEMM is HBM/MFMA-bound,
// rank is atomic-latency-bound -> they overlap on complementary pipes.
__global__ __launch_bounds__(256) void k_gemm_rank(
    const float* __restrict__ x, const unsigned short* __restrict__ WTs,
    const float* __restrict__ bias, int N,
    unsigned short* __restrict__ y, float* __restrict__ out,
    const int* __restrict__ edst, int E,
    int* __restrict__ cnt, int* __restrict__ rank) {
    __shared__ unsigned short sm[128 * 128];   // 32 KB
    int b = blockIdx.x;
    int tid = threadIdx.x;
    if (b % 5 != 0) {
        // ---- rank path (no barriers; block-uniform branch) ----
        int rb = (b / 5) * 4 + (b % 5) - 1;
        int e = rb * 256 + tid;
        if (e < E) {
            int d = edst[e];
            rank[e] = atomicAdd(&cnt[d], 1);
        }
        return;
    }
    // ---- GEMM path ----
    int gb = b / 5;
    int w = tid >> 6, l = tid & 63;
    int row0 = gb * 64 + w * 16;
    if (gb * 64 >= N) return;                 // block-uniform
    int c15 = l & 15;
    int kgrp = l >> 4;                       // 0..3
    const uint4* gs = (const uint4*)WTs;
    uint4* ss = (uint4*)sm;
    {   // stage phase-0 half of WT: linear, conflict-free b128 writes
        #pragma unroll
        for (int r = 0; r < 8; ++r) ss[r * 256 + tid] = gs[r * 256 + tid];
    }
    int arow = row0 + c15;                   // A: row = lane%16
    bool avalid = (arow < N);
    const float* xr = x + (size_t)arow * D;
    bf16x8 afrag[4];
    #pragma unroll
    for (int ks = 0; ks < 4; ++ks) {
        int k0 = ks * 32 + kgrp * 8;         // A: k = 8*(lane/16) + j
        float4 a0, a1;
        if (avalid) { a0 = *(const float4*)(xr + k0); a1 = *(const float4*)(xr + k0 + 4); }
        else { a0 = make_float4(0.f, 0.f, 0.f, 0.f); a1 = a0; }
        bf16x8 f;
        f[0] = (__bf16)a0.x; f[1] = (__bf16)a0.y; f[2] = (__bf16)a0.z; f[3] = (__bf16)a0.w;
        f[4] = (__bf16)a1.x; f[5] = (__bf16)a1.y; f[6] = (__bf16)a1.z; f[7] = (__bf16)a1.w;
        afrag[ks] = f;
    }
    __syncthreads();
    int orow = row0 + kgrp * 4;              // C/D: row = 4*(lane/16) + j
    #pragma unroll
    for (int nt = 0; nt < 8; ++nt) {         // phase 0: y = bf16(x@W_nbrs)
        int c = nt * 16 + c15;
        f32x4 acc = {0.f, 0.f, 0.f, 0.f};
        #pragma unroll
        for (int ks = 0; ks < 4; ++ks) {
            int chunk = ks * 4 + kgrp;
            const bf16x8* bp = (const bf16x8*)(sm + c * 128 + ((chunk ^ c15) << 3));
            acc = __builtin_amdgcn_mfma_f32_16x16x32_bf16(afrag[ks], *bp, acc, 0, 0, 0);
        }
        #pragma unroll
        for (int j = 0; j < 4; ++j) {
            int r = orow + j;
            if (r < N) y[(size_t)r * D + c] = f2bf(acc[j]);
        }
    }
    __syncthreads();
    {   // stage phase-1 half
        #pragma unroll
        for (int r = 0; r < 8; ++r) ss[r * 256 + tid] = gs[2048 + r * 256 + tid];
    }
    __syncthreads();
    #pragma unroll
    for (int nt = 0; nt < 8; ++nt) {         // phase 1: out = x@W_self + bias
        int c = nt * 16 + c15;
        f32x4 acc = {0.f, 0.f, 0.f, 0.f};
        #pragma unroll
        for (int ks = 0; ks < 4; ++ks) {
            int chunk = ks * 4 + kgrp;
            const bf16x8* bp = (const bf16x8*)(sm + c * 128 + ((chunk ^ c15) << 3));
            acc = __builtin_amdgcn_mfma_f32_16x16x32_bf16(afrag[ks], *bp, acc, 0, 0, 0);
        }
        float bsv = bias[c];
        #pragma unroll
        for (int j = 0; j < 4; ++j) {
            int r = orow + j;
            if (r < N) out[(size_t)r * D + c] = acc[j] + bsv;
        }
    }
}

__global__ void k_scanA(const int* __restrict__ cnt, int N,
                        int* __restrict__ ofs, int* __restrict__ bsum) {
    __shared__ int lds[1024];
    int t = threadIdx.x, i = blockIdx.x * 1024 + t;
    int v = (i < N) ? cnt[i] : 0;
    lds[t] = v; __syncthreads();
    for (int d = 1; d < 1024; d <<= 1) {
        int x = (t >= d) ? lds[t - d] : 0; __syncthreads();
        lds[t] += x; __syncthreads();
    }
    if (i < N) ofs[i] = lds[t] - v;           // local (within-block) exclusive scan
    if (t == 1023) bsum[blockIdx.x] = lds[t]; // block total
}

__global__ void k_scanB(int* __restrict__ bsum, int NB) {   // NB <= 128
    __shared__ int lds[128];
    int t = threadIdx.x;
    int v = (t < NB) ? bsum[t] : 0;
    lds[t] = v; __syncthreads();
    for (int d = 1; d < 128; d <<= 1) {
        int x = (t >= d) ? lds[t - d] : 0; __syncthreads();
        lds[t] += x; __syncthreads();
    }
    if (t < NB) bsum[t] = lds[t] - v;         // exclusive block bases
}

// No atomics: pos = ofs[d] + bsum[d>>10] + rank[e]; pure scatter of uint2.
__global__ __launch_bounds__(256) void k_fill(
    const int* __restrict__ src, const int* __restrict__ dst,
    const float* __restrict__ w, const int* __restrict__ rank, int E,
    const int* __restrict__ ofs, const int* __restrict__ bsum,
    uint2* __restrict__ sorted) {
    int e = blockIdx.x * blockDim.x + threadIdx.x;
    if (e < E) {
        int d = dst[e];
        int pos = ofs[d] + bsum[d >> 10] + rank[e];
        sorted[pos] = make_uint2((unsigned)src[e], __float_as_uint(w[e]));
    }
}

// One wave per destination node, split into 4 x 16-lane groups.
// Group g handles edges j = g, g+4, ... ; each lane loads 16 B (8 bf16 feats),
// so 4 row-gathers are in flight per iteration (8 with unroll-2).
// End: 2-round shfl_xor butterfly, lanes 0..15 wide-RMW out (512 B/wave).
__global__ __launch_bounds__(256) void k_agg(
    const unsigned short* __restrict__ y, const uint2* __restrict__ sorted,
    const int* __restrict__ ofs, const int* __restrict__ bsum,
    const int* __restrict__ cnt, int N,
    float* __restrict__ out) {
    int w = threadIdx.x >> 6, l = threadIdx.x & 63;
    int node = blockIdx.x * 4 + w;
    if (node >= N) return;
    int s = ofs[node] + bsum[node >> 10], n = cnt[node];
    int g = l >> 4, li = l & 15;
    const uint2* sp = sorted + s;
    float a0 = 0.f, a1 = 0.f, a2 = 0.f, a3 = 0.f;
    float a4 = 0.f, a5 = 0.f, a6 = 0.f, a7 = 0.f;
    int j = g;
    for (; j + 4 < n; j += 8) {
        uint2 pa = sp[j];
        uint2 pb = sp[j + 4];
        uint4 va = *(const uint4*)(y + (size_t)pa.x * D + li * 8);
        uint4 vb = *(const uint4*)(y + (size_t)pb.x * D + li * 8);
        float wa = __uint_as_float(pa.y), wb = __uint_as_float(pb.y);
        a0 += wa * bf2f(va.x & 0xFFFFu); a1 += wa * bf2f(va.x >> 16);
        a2 += wa * bf2f(va.y & 0xFFFFu); a3 += wa * bf2f(va.y >> 16);
        a4 += wa * bf2f(va.z & 0xFFFFu); a5 += wa * bf2f(va.z >> 16);
        a6 += wa * bf2f(va.w & 0xFFFFu); a7 += wa * bf2f(va.w >> 16);
        a0 += wb * bf2f(vb.x & 0xFFFFu); a1 += wb * bf2f(vb.x >> 16);
        a2 += wb * bf2f(vb.y & 0xFFFFu); a3 += wb * bf2f(vb.y >> 16);
        a4 += wb * bf2f(vb.z & 0xFFFFu); a5 += wb * bf2f(vb.z >> 16);
        a6 += wb * bf2f(vb.w & 0xFFFFu); a7 += wb * bf2f(vb.w >> 16);
    }
    if (j < n) {
        uint2 p = sp[j];
        uint4 v = *(const uint4*)(y + (size_t)p.x * D + li * 8);
        float wt = __uint_as_float(p.y);
        a0 += wt * bf2f(v.x & 0xFFFFu); a1 += wt * bf2f(v.x >> 16);
        a2 += wt * bf2f(v.y & 0xFFFFu); a3 += wt * bf2f(v.y >> 16);
        a4 += wt * bf2f(v.z & 0xFFFFu); a5 += wt * bf2f(v.z >> 16);
        a6 += wt * bf2f(v.w & 0xFFFFu); a7 += wt * bf2f(v.w >> 16);
    }
    // butterfly across the 4 groups (xor 16, then xor 32): all lanes -> full sums
    a0 += __shfl_xor(a0, 16, 64); a1 += __shfl_xor(a1, 16, 64);
    a2 += __shfl_xor(a2, 16, 64); a3 += __shfl_xor(a3, 16, 64);
    a4 += __shfl_xor(a4, 16, 64); a5 += __shfl_xor(a5, 16, 64);
    a6 += __shfl_xor(a6, 16, 64); a7 += __shfl_xor(a7, 16, 64);
    a0 += __shfl_xor(a0, 32, 64); a1 += __shfl_xor(a1, 32, 64);
    a2 += __shfl_xor(a2, 32, 64); a3 += __shfl_xor(a3, 32, 64);
    a4 += __shfl_xor(a4, 32, 64); a5 += __shfl_xor(a5, 32, 64);
    a6 += __shfl_xor(a6, 32, 64); a7 += __shfl_xor(a7, 32, 64);
    if (l < 16) {   // lanes 0..15 each own features [li*8, li*8+8)
        float4* op = (float4*)(out + (size_t)node * D + li * 8);
        float4 o0 = op[0], o1 = op[1];
        o0.x += a0; o0.y += a1; o0.z += a2; o0.w += a3;
        o1.x += a4; o1.y += a5; o1.z += a6; o1.w += a7;
        op[0] = o0; op[1] = o1;
    }
}

extern "C" void kernel_launch(void* const* d_in, const int* in_sizes, int n_in,
                              void* d_out, int out_size, void* d_ws, size_t ws_size,
                              hipStream_t stream) {
    const float* x    = (const float*)d_in[0];
    const int*   esrc = (const int*)d_in[1];
    const int*   edst = (const int*)d_in[2];
    const float* ew   = (const float*)d_in[3];
    const float* Wn   = (const float*)d_in[4];
    const float* Wsf  = (const float*)d_in[5];
    const float* bias = (const float*)d_in[6];
    float* out = (float*)d_out;
    int N = in_sizes[0] / D;
    int E = in_sizes[1];

    char* ws = (char*)d_ws;
    size_t off = 0;
    unsigned short* WTs = (unsigned short*)(ws + off); off += 256 * 128 * sizeof(unsigned short);
    unsigned short* yb  = (unsigned short*)(ws + off); off += (size_t)N * D * sizeof(unsigned short);
    off = (off + 255) & ~(size_t)255;
    int* cnt  = (int*)(ws + off); off += (size_t)N * 4; off = (off + 255) & ~(size_t)255;
    int* ofs  = (int*)(ws + off); off += (size_t)N * 4; off = (off + 255) & ~(size_t)255;
    int* bsum = (int*)(ws + off); off += 1024;
    int* rank = (int*)(ws + off); off += (size_t)E * 4; off = (off + 255) & ~(size_t)255;
    uint2* sorted = (uint2*)(ws + off); off += (size_t)E * 8;

    hipMemsetAsync(cnt, 0, (size_t)N * 4, stream);

    k_build_wt<<<128, 256, 0, stream>>>(Wn, Wsf, WTs);

    int GB = (N + 63) / 64;
    int RB = (E + 255) / 256;
    int G5 = (GB > (RB + 3) / 4 ? GB : (RB + 3) / 4) * 5;
    k_gemm_rank<<<G5, 256, 0, stream>>>(x, WTs, bias, N, yb, out,
                                        edst, E, cnt, rank);

    int NB = (N + 1023) / 1024;
    k_scanA<<<NB, 1024, 0, stream>>>(cnt, N, ofs, bsum);
    k_scanB<<<1, 128, 0, stream>>>(bsum, NB);
    k_fill<<<(E + 255) / 256, 256, 0, stream>>>(esrc, edst, ew, rank, E, ofs, bsum, sorted);

    k_agg<<<(N + 3) / 4, 256, 0, stream>>>(yb, sorted, ofs, bsum, cnt, N, out);
}

// Round 4
// 293.314 us; speedup vs baseline: 1.6911x; 1.0366x over previous
//
#include <hip/hip_runtime.h>
#include <hip/hip_bf16.h>

#define D 128

typedef __bf16 bf16x8 __attribute__((ext_vector_type(8)));
typedef unsigned short u16x8 __attribute__((ext_vector_type(8)));
typedef float f32x4 __attribute__((ext_vector_type(4)));

__device__ __forceinline__ unsigned short f2bf(float f) {
    unsigned u = __float_as_uint(f);
    u += 0x7FFFu + ((u >> 16) & 1u);
    return (unsigned short)(u >> 16);
}
__device__ __forceinline__ float bf2f(unsigned u16) {
    return __uint_as_float(u16 << 16);
}

// Build W = [W_nbrs | W_self]^T as bf16, XOR-swizzled so GEMM can stage it
// linearly into LDS and read B fragments conflict-free.
// Element (k, c) -> WTs[c*128 + (((k>>3) ^ (c&15)) << 3) + (k&7)]
// Also zeroes cnt[] (replaces a separate memset dispatch).
__global__ void k_build_wt(const float* __restrict__ Wn, const float* __restrict__ Ws,
                           unsigned short* __restrict__ WTs,
                           int* __restrict__ cnt, int N) {
    int g = blockIdx.x * blockDim.x + threadIdx.x;   // 0..32767
    int k = g >> 8;          // 0..127
    int c = g & 255;         // 0..255 (coalesced reads along c)
    float v = (c < 128) ? Wn[k * 128 + c] : Ws[k * 128 + (c - 128)];
    int chunk = k >> 3;
    WTs[c * 128 + (((chunk ^ (c & 15)) << 3) | (k & 7))] = f2bf(v);
    for (int i = g; i < N; i += 32768) cnt[i] = 0;
}

// Fused 1:1: even blocks = GEMM tile (64 rows), odd blocks = rank pass
// (1024 edges/block, 4 independent atomic chains per thread).
// GEMM phase 0 stores y in nt-major permuted layout y'[r][c15*8+nt] =
// C[r][nt*16+c15] -> one 16-B store per (thread, row). Phase 1 transposes
// C through LDS -> 8 fully-coalesced 1-KB wave stores.
__global__ __launch_bounds__(256) void k_gemm_rank(
    const float* __restrict__ x, const unsigned short* __restrict__ WTs,
    const float* __restrict__ bias, int N,
    unsigned short* __restrict__ y, float* __restrict__ out,
    const int* __restrict__ edst, int E,
    int* __restrict__ cnt, int* __restrict__ rank) {
    __shared__ unsigned short sm[128 * 128];   // 32 KB; reused as 64x128 f32
    int b = blockIdx.x;
    int tid = threadIdx.x;
    if (b & 1) {
        // ---- rank path ----
        int e0 = (b >> 1) * 1024 + tid;
        #pragma unroll
        for (int k = 0; k < 4; ++k) {
            int e = e0 + k * 256;
            if (e < E) {
                int d = edst[e];
                rank[e] = atomicAdd(&cnt[d], 1);
            }
        }
        return;
    }
    // ---- GEMM path ----
    int gb = b >> 1;
    int brow = gb * 64;
    if (brow >= N) return;                   // block-uniform
    int w = tid >> 6, l = tid & 63;
    int row0 = brow + w * 16;
    int c15 = l & 15;
    int kgrp = l >> 4;                       // 0..3
    const uint4* gs = (const uint4*)WTs;
    uint4* ss = (uint4*)sm;
    {   // stage phase-0 half of WT: linear, conflict-free b128 writes
        #pragma unroll
        for (int r = 0; r < 8; ++r) ss[r * 256 + tid] = gs[r * 256 + tid];
    }
    int arow = row0 + c15;                   // A: row = lane%16
    bool avalid = (arow < N);
    const float* xr = x + (size_t)arow * D;
    bf16x8 afrag[4];
    #pragma unroll
    for (int ks = 0; ks < 4; ++ks) {
        int k0 = ks * 32 + kgrp * 8;         // A: k = 8*(lane/16) + j
        float4 a0, a1;
        if (avalid) { a0 = *(const float4*)(xr + k0); a1 = *(const float4*)(xr + k0 + 4); }
        else { a0 = make_float4(0.f, 0.f, 0.f, 0.f); a1 = a0; }
        bf16x8 f;
        f[0] = (__bf16)a0.x; f[1] = (__bf16)a0.y; f[2] = (__bf16)a0.z; f[3] = (__bf16)a0.w;
        f[4] = (__bf16)a1.x; f[5] = (__bf16)a1.y; f[6] = (__bf16)a1.z; f[7] = (__bf16)a1.w;
        afrag[ks] = f;
    }
    __syncthreads();
    int orow = row0 + kgrp * 4;              // C/D: row = 4*(lane/16) + j
    f32x4 acc[8];
    #pragma unroll
    for (int nt = 0; nt < 8; ++nt) {         // phase 0: y = bf16(x@W_nbrs)
        int c = nt * 16 + c15;
        f32x4 a = {0.f, 0.f, 0.f, 0.f};
        #pragma unroll
        for (int ks = 0; ks < 4; ++ks) {
            int chunk = ks * 4 + kgrp;
            const bf16x8* bp = (const bf16x8*)(sm + c * 128 + ((chunk ^ c15) << 3));
            a = __builtin_amdgcn_mfma_f32_16x16x32_bf16(afrag[ks], *bp, a, 0, 0, 0);
        }
        acc[nt] = a;
    }
    // permuted y store: y'[r][c15*8+nt] = C[r][nt*16+c15]; 16 B per (thread,row)
    #pragma unroll
    for (int j = 0; j < 4; ++j) {
        int r = orow + j;
        if (r < N) {
            u16x8 f;
            #pragma unroll
            for (int nt = 0; nt < 8; ++nt) f[nt] = f2bf(acc[nt][j]);
            *(u16x8*)(y + (size_t)r * D + c15 * 8) = f;
        }
    }
    __syncthreads();
    {   // stage phase-1 half
        #pragma unroll
        for (int r = 0; r < 8; ++r) ss[r * 256 + tid] = gs[2048 + r * 256 + tid];
    }
    __syncthreads();
    #pragma unroll
    for (int nt = 0; nt < 8; ++nt) {         // phase 1: x@W_self
        int c = nt * 16 + c15;
        f32x4 a = {0.f, 0.f, 0.f, 0.f};
        #pragma unroll
        for (int ks = 0; ks < 4; ++ks) {
            int chunk = ks * 4 + kgrp;
            const bf16x8* bp = (const bf16x8*)(sm + c * 128 + ((chunk ^ c15) << 3));
            a = __builtin_amdgcn_mfma_f32_16x16x32_bf16(afrag[ks], *bp, a, 0, 0, 0);
        }
        acc[nt] = a;
    }
    __syncthreads();                          // done reading B1 from LDS
    float* smf = (float*)sm;                  // 64x128 f32 C-tile
    int lr0 = w * 16 + kgrp * 4;
    #pragma unroll
    for (int nt = 0; nt < 8; ++nt) {
        #pragma unroll
        for (int j = 0; j < 4; ++j)
            smf[(lr0 + j) * 128 + nt * 16 + c15] = acc[nt][j];
    }
    __syncthreads();
    float4 bv = *(const float4*)&bias[(tid * 4) & 127];
    #pragma unroll
    for (int k = 0; k < 8; ++k) {            // coalesced 1-KB wave stores
        int f = tid * 4 + k * 1024;
        int gr = brow + (f >> 7);
        if (gr < N) {
            float4 c4 = *(float4*)&smf[f];
            c4.x += bv.x; c4.y += bv.y; c4.z += bv.z; c4.w += bv.w;
            *(float4*)(out + (size_t)brow * D + f) = c4;
        }
    }
}

__global__ void k_scanA(const int* __restrict__ cnt, int N,
                        int* __restrict__ ofs, int* __restrict__ bsum) {
    __shared__ int lds[1024];
    int t = threadIdx.x, i = blockIdx.x * 1024 + t;
    int v = (i < N) ? cnt[i] : 0;
    lds[t] = v; __syncthreads();
    for (int d = 1; d < 1024; d <<= 1) {
        int x = (t >= d) ? lds[t - d] : 0; __syncthreads();
        lds[t] += x; __syncthreads();
    }
    if (i < N) ofs[i] = lds[t] - v;           // local (within-block) exclusive scan
    if (t == 1023) bsum[blockIdx.x] = lds[t]; // block total
}

__global__ void k_scanB(int* __restrict__ bsum, int NB) {   // NB <= 128
    __shared__ int lds[128];
    int t = threadIdx.x;
    int v = (t < NB) ? bsum[t] : 0;
    lds[t] = v; __syncthreads();
    for (int d = 1; d < 128; d <<= 1) {
        int x = (t >= d) ? lds[t - d] : 0; __syncthreads();
        lds[t] += x; __syncthreads();
    }
    if (t < NB) bsum[t] = lds[t] - v;         // exclusive block bases
}

// No atomics: pos = ofs[d] + bsum[d>>10] + rank[e]; pure scatter of uint2.
__global__ __launch_bounds__(256) void k_fill(
    const int* __restrict__ src, const int* __restrict__ dst,
    const float* __restrict__ w, const int* __restrict__ rank, int E,
    const int* __restrict__ ofs, const int* __restrict__ bsum,
    uint2* __restrict__ sorted) {
    int e = blockIdx.x * blockDim.x + threadIdx.x;
    if (e < E) {
        int d = dst[e];
        int pos = ofs[d] + bsum[d >> 10] + rank[e];
        sorted[pos] = make_uint2((unsigned)src[e], __float_as_uint(w[e]));
    }
}

// One wave per destination node, 4 x 16-lane groups, 8 gathers in flight.
// y is in nt-major permuted layout: y'[r][li*8+m] = C[r][m*16+li], so lane li's
// accumulator a_m maps to out column li + 16*m (still full-64B-line RMWs).
__global__ __launch_bounds__(256) void k_agg(
    const unsigned short* __restrict__ y, const uint2* __restrict__ sorted,
    const int* __restrict__ ofs, const int* __restrict__ bsum,
    const int* __restrict__ cnt, int N,
    float* __restrict__ out) {
    int w = threadIdx.x >> 6, l = threadIdx.x & 63;
    int node = blockIdx.x * 4 + w;
    if (node >= N) return;
    int s = ofs[node] + bsum[node >> 10], n = cnt[node];
    int g = l >> 4, li = l & 15;
    const uint2* sp = sorted + s;
    float a0 = 0.f, a1 = 0.f, a2 = 0.f, a3 = 0.f;
    float a4 = 0.f, a5 = 0.f, a6 = 0.f, a7 = 0.f;
    int j = g;
    for (; j + 4 < n; j += 8) {
        uint2 pa = sp[j];
        uint2 pb = sp[j + 4];
        uint4 va = *(const uint4*)(y + (size_t)pa.x * D + li * 8);
        uint4 vb = *(const uint4*)(y + (size_t)pb.x * D + li * 8);
        float wa = __uint_as_float(pa.y), wb = __uint_as_float(pb.y);
        a0 += wa * bf2f(va.x & 0xFFFFu); a1 += wa * bf2f(va.x >> 16);
        a2 += wa * bf2f(va.y & 0xFFFFu); a3 += wa * bf2f(va.y >> 16);
        a4 += wa * bf2f(va.z & 0xFFFFu); a5 += wa * bf2f(va.z >> 16);
        a6 += wa * bf2f(va.w & 0xFFFFu); a7 += wa * bf2f(va.w >> 16);
        a0 += wb * bf2f(vb.x & 0xFFFFu); a1 += wb * bf2f(vb.x >> 16);
        a2 += wb * bf2f(vb.y & 0xFFFFu); a3 += wb * bf2f(vb.y >> 16);
        a4 += wb * bf2f(vb.z & 0xFFFFu); a5 += wb * bf2f(vb.z >> 16);
        a6 += wb * bf2f(vb.w & 0xFFFFu); a7 += wb * bf2f(vb.w >> 16);
    }
    if (j < n) {
        uint2 p = sp[j];
        uint4 v = *(const uint4*)(y + (size_t)p.x * D + li * 8);
        float wt = __uint_as_float(p.y);
        a0 += wt * bf2f(v.x & 0xFFFFu); a1 += wt * bf2f(v.x >> 16);
        a2 += wt * bf2f(v.y & 0xFFFFu); a3 += wt * bf2f(v.y >> 16);
        a4 += wt * bf2f(v.z & 0xFFFFu); a5 += wt * bf2f(v.z >> 16);
        a6 += wt * bf2f(v.w & 0xFFFFu); a7 += wt * bf2f(v.w >> 16);
    }
    // butterfly across the 4 groups (xor 16, then xor 32): all lanes -> full sums
    a0 += __shfl_xor(a0, 16, 64); a1 += __shfl_xor(a1, 16, 64);
    a2 += __shfl_xor(a2, 16, 64); a3 += __shfl_xor(a3, 16, 64);
    a4 += __shfl_xor(a4, 16, 64); a5 += __shfl_xor(a5, 16, 64);
    a6 += __shfl_xor(a6, 16, 64); a7 += __shfl_xor(a7, 16, 64);
    a0 += __shfl_xor(a0, 32, 64); a1 += __shfl_xor(a1, 32, 64);
    a2 += __shfl_xor(a2, 32, 64); a3 += __shfl_xor(a3, 32, 64);
    a4 += __shfl_xor(a4, 32, 64); a5 += __shfl_xor(a5, 32, 64);
    a6 += __shfl_xor(a6, 32, 64); a7 += __shfl_xor(a7, 32, 64);
    if (l < 16) {   // lane li owns cols li+16m; each m-group is one 64-B line
        float* op = out + (size_t)node * D + li;
        op[0]   += a0; op[16]  += a1; op[32]  += a2; op[48]  += a3;
        op[64]  += a4; op[80]  += a5; op[96]  += a6; op[112] += a7;
    }
}

extern "C" void kernel_launch(void* const* d_in, const int* in_sizes, int n_in,
                              void* d_out, int out_size, void* d_ws, size_t ws_size,
                              hipStream_t stream) {
    const float* x    = (const float*)d_in[0];
    const int*   esrc = (const int*)d_in[1];
    const int*   edst = (const int*)d_in[2];
    const float* ew   = (const float*)d_in[3];
    const float* Wn   = (const float*)d_in[4];
    const float* Wsf  = (const float*)d_in[5];
    const float* bias = (const float*)d_in[6];
    float* out = (float*)d_out;
    int N = in_sizes[0] / D;
    int E = in_sizes[1];

    char* ws = (char*)d_ws;
    size_t off = 0;
    unsigned short* WTs = (unsigned short*)(ws + off); off += 256 * 128 * sizeof(unsigned short);
    unsigned short* yb  = (unsigned short*)(ws + off); off += (size_t)N * D * sizeof(unsigned short);
    off = (off + 255) & ~(size_t)255;
    int* cnt  = (int*)(ws + off); off += (size_t)N * 4; off = (off + 255) & ~(size_t)255;
    int* ofs  = (int*)(ws + off); off += (size_t)N * 4; off = (off + 255) & ~(size_t)255;
    int* bsum = (int*)(ws + off); off += 1024;
    int* rank = (int*)(ws + off); off += (size_t)E * 4; off = (off + 255) & ~(size_t)255;
    uint2* sorted = (uint2*)(ws + off); off += (size_t)E * 8;

    k_build_wt<<<128, 256, 0, stream>>>(Wn, Wsf, WTs, cnt, N);

    int GB = (N + 63) / 64;
    int RB = (E + 1023) / 1024;
    int G2 = (GB > RB ? GB : RB) * 2;
    k_gemm_rank<<<G2, 256, 0, stream>>>(x, WTs, bias, N, yb, out,
                                        edst, E, cnt, rank);

    int NB = (N + 1023) / 1024;
    k_scanA<<<NB, 1024, 0, stream>>>(cnt, N, ofs, bsum);
    k_scanB<<<1, 128, 0, stream>>>(bsum, NB);
    k_fill<<<(E + 255) / 256, 256, 0, stream>>>(esrc, edst, ew, rank, E, ofs, bsum, sorted);

    k_agg<<<(N + 3) / 4, 256, 0, stream>>>(yb, sorted, ofs, bsum, cnt, N, out);
}